// Round 14
// baseline (1083.174 us; speedup 1.0000x reference)
//
#include <hip/hip_runtime.h>
#include <math.h>

typedef short bf16x8 __attribute__((ext_vector_type(8)));
typedef float f32x4 __attribute__((ext_vector_type(4)));
typedef float f32x2 __attribute__((ext_vector_type(2)));
typedef unsigned int uint;
typedef uint u32x4 __attribute__((ext_vector_type(4)));
typedef unsigned long long ull;
typedef unsigned short ushort;

#define Bz 32
#define Tz 50
#define Sz 40
#define Vz 32000
#define Dz 512
#define Hz 1024
#define Mz 1600
#define Mp 1664
#define CAP 1024
#define NSLOT 51   // rotating hx slots: 0 = init, t+1 written at step t

__device__ __forceinline__ ushort f2bf(float f) {           // round-to-nearest-even
    uint u = __builtin_bit_cast(uint, f);
    return (ushort)((u + 0x7FFFu + ((u >> 16) & 1u)) >> 16);
}
__device__ __forceinline__ float bf2f(ushort h) {
    uint u = ((uint)h) << 16;
    return __builtin_bit_cast(float, u);
}
// truncation split: f = hi + rem
__device__ __forceinline__ void splitf(float f, ushort& hi, ushort& lo) {
    uint u = __builtin_bit_cast(uint, f);
    hi = (ushort)(u >> 16);
    float rem = f - __builtin_bit_cast(float, u & 0xFFFF0000u);
    lo = (ushort)(__builtin_bit_cast(uint, rem) >> 16);
}
// RN split: hi = RN(f), lo = RN(f - hi)
__device__ __forceinline__ void splitrn(float f, ushort& hi, ushort& lo) {
    hi = f2bf(f);
    lo = f2bf(f - bf2f(hi));
}
__device__ __forceinline__ float sigf(float x) { return 1.f / (1.f + expf(-x)); }

// sc1 scalar ops: cache-bypassing (flags only — must never be cached).
// "=&v" early-clobber is ESSENTIAL (R9 failure: dest aliased the addr pair).
__device__ __forceinline__ uint ld_sc1(const uint* p) {
    uint v;
    asm volatile("global_load_dword %0, %1, off sc0 sc1\n\ts_waitcnt vmcnt(0)"
                 : "=&v"(v) : "v"(p) : "memory");
    return v;
}
__device__ __forceinline__ void st_sc1(uint* p, uint v) {
    asm volatile("global_store_dword %0, %1, off sc0 sc1" :: "v"(p), "v"(v) : "memory");
}

// ---------- k_pre ----------
__global__ __launch_bounds__(256) void k_pre(ushort* hxA_hi, ushort* hxA_lo, float* cx,
                                             ushort* AH_hi, ushort* AH_lo, uint* flags,
                                             const float* h0, const float* c0) {
    int gid = blockIdx.x * 256 + threadIdx.x;
    if (gid < 32768) {
        float v = h0[gid];
        ushort hi, lo;
        splitf(v, hi, lo);
        hxA_hi[gid] = hi;          // slot 0
        hxA_lo[gid] = lo;
    } else if (gid < 65536) {
        cx[gid - 32768] = c0[gid - 32768];
    } else if (gid < 196608) {
        int g = gid - 65536;               // AH pad rows 1600..1663
        AH_hi[(long)Mz * 2048 + g] = 0;
        AH_lo[(long)Mz * 2048 + g] = 0;
    } else if (gid < 196608 + 2048) {
        st_sc1(&flags[gid - 196608], 0u);  // replay-safe reset
    }
}

// ---------- k_wsplit: fp32 -> bf16 hi/lo planes (truncation; recurrence weights) ----------
__global__ __launch_bounds__(256) void k_wsplit(const float* __restrict__ src,
                                                ushort* __restrict__ hi, ushort* __restrict__ lo,
                                                int n4) {
    int stride = gridDim.x * 256;
    for (int i = blockIdx.x * 256 + threadIdx.x; i < n4; i += stride) {
        float4 f = *(const float4*)(src + (long)i * 4);
        float vv[4] = {f.x, f.y, f.z, f.w};
        ushort h[4], l[4];
#pragma unroll
        for (int e = 0; e < 4; ++e) splitf(vv[e], h[e], l[e]);
        uint2 hp, lp;
        hp.x = (uint)h[0] | ((uint)h[1] << 16);
        hp.y = (uint)h[2] | ((uint)h[3] << 16);
        lp.x = (uint)l[0] | ((uint)l[1] << 16);
        lp.y = (uint)l[2] | ((uint)l[3] << 16);
        *(uint2*)(hi + (long)i * 4) = hp;
        *(uint2*)(lo + (long)i * 4) = lp;
    }
}

// ---------- k_wbf16: fp32 -> single bf16 RN plane (fallback for Wvoc) ----------
__global__ __launch_bounds__(256) void k_wbf16(const float* __restrict__ src,
                                               ushort* __restrict__ dst, int n4) {
    int stride = gridDim.x * 256;
    for (int i = blockIdx.x * 256 + threadIdx.x; i < n4; i += stride) {
        float4 f = *(const float4*)(src + (long)i * 4);
        uint2 hp;
        hp.x = (uint)f2bf(f.x) | ((uint)f2bf(f.y) << 16);
        hp.y = (uint)f2bf(f.z) | ((uint)f2bf(f.w) << 16);
        *(uint2*)(dst + (long)i * 4) = hp;
    }
}

// ---------- k_xgemm: gates_x = emb[tok] @ Wih^T + bih + bhh (split-bf16 MFMA) ----------
__global__ __launch_bounds__(256, 1) void k_xgemm(const float* __restrict__ emb,
                                                  const int* __restrict__ tok,
                                                  const float* __restrict__ Wih,
                                                  const float* __restrict__ bih,
                                                  const float* __restrict__ bhh,
                                                  float* __restrict__ gx) {
    __shared__ ushort sAh[128][40];
    __shared__ ushort sAl[128][40];
    __shared__ ushort sBh[128][40];
    __shared__ ushort sBl[128][40];
    int bid = blockIdx.x;
    int mt = bid >> 5, nt = bid & 31;
    int tid = threadIdx.x;
    int row = tid >> 1, half = tid & 1;
    int wv = tid >> 6, lane = tid & 63;
    int wr = wv >> 1, wc = wv & 1;
    int m0 = wr * 64, n0 = wc * 64;
    int r16 = lane & 15, kg = lane >> 4, k0 = kg * 8;

    f32x4 acc[4][4];
#pragma unroll
    for (int i = 0; i < 4; i++)
#pragma unroll
        for (int j = 0; j < 4; j++) acc[i][j] = (f32x4){0.f, 0.f, 0.f, 0.f};

    int r = mt * 128 + row;
    int tk = (r < Mz) ? tok[r] : 0;
    const float* arow = emb + (long)tk * Dz;
    const float* brow = Wih + (long)(nt * 128 + row) * Dz;

    for (int kb = 0; kb < Dz; kb += 32) {
        {
            ushort hh[16], ll[16];
#pragma unroll
            for (int q = 0; q < 16; q += 4) {
                float4 w4 = (r < Mz) ? *(const float4*)(arow + kb + half * 16 + q)
                                     : (float4){0.f, 0.f, 0.f, 0.f};
                float vv[4] = {w4.x, w4.y, w4.z, w4.w};
#pragma unroll
                for (int e = 0; e < 4; ++e) splitf(vv[e], hh[q + e], ll[q + e]);
            }
            *(uint4*)&sAh[row][half * 16]     = *(uint4*)&hh[0];
            *(uint4*)&sAh[row][half * 16 + 8] = *(uint4*)&hh[8];
            *(uint4*)&sAl[row][half * 16]     = *(uint4*)&ll[0];
            *(uint4*)&sAl[row][half * 16 + 8] = *(uint4*)&ll[8];
        }
        {
            ushort hh[16], ll[16];
#pragma unroll
            for (int q = 0; q < 16; q += 4) {
                float4 w4 = *(const float4*)(brow + kb + half * 16 + q);
                float vv[4] = {w4.x, w4.y, w4.z, w4.w};
#pragma unroll
                for (int e = 0; e < 4; ++e) splitf(vv[e], hh[q + e], ll[q + e]);
            }
            *(uint4*)&sBh[row][half * 16]     = *(uint4*)&hh[0];
            *(uint4*)&sBh[row][half * 16 + 8] = *(uint4*)&hh[8];
            *(uint4*)&sBl[row][half * 16]     = *(uint4*)&ll[0];
            *(uint4*)&sBl[row][half * 16 + 8] = *(uint4*)&ll[8];
        }
        __syncthreads();
        bf16x8 af[4], alf[4], bhf[4], blf[4];
#pragma unroll
        for (int i = 0; i < 4; ++i) {
            af[i]  = *(const bf16x8*)&sAh[m0 + i * 16 + r16][k0];
            alf[i] = *(const bf16x8*)&sAl[m0 + i * 16 + r16][k0];
            bhf[i] = *(const bf16x8*)&sBh[n0 + i * 16 + r16][k0];
            blf[i] = *(const bf16x8*)&sBl[n0 + i * 16 + r16][k0];
        }
#pragma unroll
        for (int i = 0; i < 4; ++i)
#pragma unroll
            for (int jn = 0; jn < 4; ++jn) {
                acc[i][jn] = __builtin_amdgcn_mfma_f32_16x16x32_bf16(af[i],  bhf[jn], acc[i][jn], 0, 0, 0);
                acc[i][jn] = __builtin_amdgcn_mfma_f32_16x16x32_bf16(af[i],  blf[jn], acc[i][jn], 0, 0, 0);
                acc[i][jn] = __builtin_amdgcn_mfma_f32_16x16x32_bf16(alf[i], bhf[jn], acc[i][jn], 0, 0, 0);
            }
        __syncthreads();
    }
#pragma unroll
    for (int i = 0; i < 4; ++i) {
        int gr0 = mt * 128 + m0 + i * 16 + kg * 4;
#pragma unroll
        for (int reg = 0; reg < 4; ++reg) {
            int gr = gr0 + reg;
            if (gr >= Mz) continue;
#pragma unroll
            for (int jn = 0; jn < 4; ++jn) {
                int gc = nt * 128 + n0 + jn * 16 + r16;
                gx[(long)gr * 4096 + gc] = acc[i][jn][reg] + bih[gc] + bhh[gc];
            }
        }
    }
}

// ---------- k_recfused8: rotating hx slots; sc0 (L2-cached) staging; sc1 flags ----------
// Mechanism: hx[t] addresses are never reused within a launch -> consumer sc0 reads
// can allocate in the XCD L2 with no staleness; 12 WGs/XCD share one LLC fetch (8x dedup).
__global__ __launch_bounds__(512, 1) void k_recfused8(
    const float* __restrict__ gx,
    const ushort* __restrict__ Whi, const ushort* __restrict__ Wlo,
    ushort* __restrict__ hxA_hi, ushort* __restrict__ hxA_lo,
    float* __restrict__ hxh, float* __restrict__ cx,
    const float* __restrict__ enc,
    ushort* __restrict__ AH_hi, ushort* __restrict__ AH_lo,
    uint* flags,
    const float* __restrict__ Wvoc, ushort* __restrict__ Wvh,
    int do_wsplit) {
    __shared__ u32x4 stg4[8192];     // 128KB: [plane][kslot 128][row 32 rotated]; sg aliased later
    __shared__ float hxs[Hz];
    __shared__ float sc[64];
    __shared__ float aw[64];
    int wid = blockIdx.x, tid = threadIdx.x;

    if (wid >= 96) {
        if (do_wsplit) {               // fused Wvoc fp32 -> bf16 RN on otherwise-idle CUs
            int n4 = Vz * Hz / 4;
            int stride = 160 * 512;
            for (int i = (wid - 96) * 512 + tid; i < n4; i += stride) {
                float4 f = *(const float4*)(Wvoc + (long)i * 4);
                uint2 hp;
                hp.x = (uint)f2bf(f.x) | ((uint)f2bf(f.y) << 16);
                hp.y = (uint)f2bf(f.z) | ((uint)f2bf(f.w) << 16);
                *(uint2*)(Wvh + (long)i * 4) = hp;
            }
        }
        return;
    }

    int lane = tid & 63, kh = tid >> 6;

    for (int t = 0; t <= Tz; ++t) {
        if (wid < 64) {
            if (t < Tz) {
                int w = wid;
                long rdoff = (long)t * 32768;          // read slot t
                long wroff = (long)(t + 1) * 32768;    // write slot t+1
                // ---- wave kh: poll its 8 producers (flags >= t) ----
                {
                    bool done = false;
                    while (!done) {
                        uint f = 0xFFFFFFFFu;
                        if (lane < 8) f = ld_sc1(&flags[(kh * 8 + lane) * 16]);
                        done = (bool)__all(f >= (uint)t);
                        if (!done) __builtin_amdgcn_s_sleep(1);
                    }
                }
                // ---- stage own K-slice (sc0: L2-allocating; slot-t addresses fresh) ----
                int kslot = kh * 16 + (lane & 15);
                int rowb = (lane >> 4) * 8;
                const ushort* planes[2] = { hxA_hi + rdoff, hxA_lo + rdoff };
#pragma unroll
                for (int plane = 0; plane < 2; ++plane) {
                    const ushort* b0 = planes[plane] + (long)rowb * 1024 + kslot * 8;
                    u32x4 d0, d1, d2, d3, d4, d5, d6, d7;
                    asm volatile(
                        "global_load_dwordx4 %0, %8, off sc0\n\t"
                        "global_load_dwordx4 %1, %9, off sc0\n\t"
                        "global_load_dwordx4 %2, %10, off sc0\n\t"
                        "global_load_dwordx4 %3, %11, off sc0\n\t"
                        "global_load_dwordx4 %4, %12, off sc0\n\t"
                        "global_load_dwordx4 %5, %13, off sc0\n\t"
                        "global_load_dwordx4 %6, %14, off sc0\n\t"
                        "global_load_dwordx4 %7, %15, off sc0\n\t"
                        "s_waitcnt vmcnt(0)"
                        : "=&v"(d0), "=&v"(d1), "=&v"(d2), "=&v"(d3),
                          "=&v"(d4), "=&v"(d5), "=&v"(d6), "=&v"(d7)
                        : "v"(b0), "v"(b0 + 1024), "v"(b0 + 2048), "v"(b0 + 3072),
                          "v"(b0 + 4096), "v"(b0 + 5120), "v"(b0 + 6144), "v"(b0 + 7168)
                        : "memory");
                    int li = plane * 4096 + kslot * 32;
                    stg4[li + ((rowb + 0 + kslot) & 31)] = d0;
                    stg4[li + ((rowb + 1 + kslot) & 31)] = d1;
                    stg4[li + ((rowb + 2 + kslot) & 31)] = d2;
                    stg4[li + ((rowb + 3 + kslot) & 31)] = d3;
                    stg4[li + ((rowb + 4 + kslot) & 31)] = d4;
                    stg4[li + ((rowb + 5 + kslot) & 31)] = d5;
                    stg4[li + ((rowb + 6 + kslot) & 31)] = d6;
                    stg4[li + ((rowb + 7 + kslot) & 31)] = d7;
                }
                // ---- MFMA: wave kh, its K-slice, all 4 gates ----
                int r16 = lane & 15, kg = lane >> 4;
                int jbase = w * 16 + r16;
                const ushort* whbase = Whi + (long)jbase * 1024;
                const ushort* wlbase = Wlo + (long)jbase * 1024;
                f32x4 acc[2][4];
#pragma unroll
                for (int i = 0; i < 2; ++i)
#pragma unroll
                    for (int v = 0; v < 4; ++v) acc[i][v] = (f32x4){0.f, 0.f, 0.f, 0.f};
#pragma unroll
                for (int it = 0; it < 4; ++it) {
                    int ksl = kh * 16 + it * 4 + kg;
                    int k0 = ksl * 8;
                    bf16x8 a_h0 = *(const bf16x8*)&stg4[       ksl * 32 + ((r16 + ksl) & 31)];
                    bf16x8 a_l0 = *(const bf16x8*)&stg4[4096 + ksl * 32 + ((r16 + ksl) & 31)];
                    bf16x8 a_h1 = *(const bf16x8*)&stg4[       ksl * 32 + ((16 + r16 + ksl) & 31)];
                    bf16x8 a_l1 = *(const bf16x8*)&stg4[4096 + ksl * 32 + ((16 + r16 + ksl) & 31)];
                    bf16x8 bh[4], bl[4];
#pragma unroll
                    for (int v = 0; v < 4; ++v) {
                        bh[v] = *(const bf16x8*)(whbase + ((long)v << 20) + k0);
                        bl[v] = *(const bf16x8*)(wlbase + ((long)v << 20) + k0);
                    }
#pragma unroll
                    for (int v = 0; v < 4; ++v) {
                        acc[0][v] = __builtin_amdgcn_mfma_f32_16x16x32_bf16(a_h0, bh[v], acc[0][v], 0, 0, 0);
                        acc[0][v] = __builtin_amdgcn_mfma_f32_16x16x32_bf16(a_l0, bh[v], acc[0][v], 0, 0, 0);
                        acc[0][v] = __builtin_amdgcn_mfma_f32_16x16x32_bf16(a_h0, bl[v], acc[0][v], 0, 0, 0);
                        acc[1][v] = __builtin_amdgcn_mfma_f32_16x16x32_bf16(a_h1, bh[v], acc[1][v], 0, 0, 0);
                        acc[1][v] = __builtin_amdgcn_mfma_f32_16x16x32_bf16(a_l1, bh[v], acc[1][v], 0, 0, 0);
                        acc[1][v] = __builtin_amdgcn_mfma_f32_16x16x32_bf16(a_h1, bl[v], acc[1][v], 0, 0, 0);
                    }
                }
                __syncthreads();                 // staged A dead; alias sg onto stg4
                float* sgp = (float*)stg4;       // sg[kh 8][v 4][b 32][h16 16] = 64KB
#pragma unroll
                for (int i = 0; i < 2; ++i)
#pragma unroll
                    for (int v = 0; v < 4; ++v)
#pragma unroll
                        for (int reg = 0; reg < 4; ++reg)
                            sgp[(((kh * 4 + v) * 32) + i * 16 + kg * 4 + reg) * 16 + r16] = acc[i][v][reg];
                __syncthreads();
                // ---- cell: thread = (b, h16) ----
                int b = tid >> 4, h16 = tid & 15;
                int hg = w * 16 + h16;
                const float* gxr = gx + ((long)b * Tz + t) * 4096 + hg;
                float g0 = 0.f, g1 = 0.f, g2 = 0.f, g3 = 0.f;
#pragma unroll
                for (int khh = 0; khh < 8; ++khh) {
                    g0 += sgp[((khh * 4 + 0) * 32 + b) * 16 + h16];
                    g1 += sgp[((khh * 4 + 1) * 32 + b) * 16 + h16];
                    g2 += sgp[((khh * 4 + 2) * 32 + b) * 16 + h16];
                    g3 += sgp[((khh * 4 + 3) * 32 + b) * 16 + h16];
                }
                g0 += gxr[0]; g1 += gxr[1024]; g2 += gxr[2048]; g3 += gxr[3072];
                long ci = (long)b * Hz + hg;
                float c = sigf(g1) * cx[ci] + sigf(g0) * tanhf(g2);
                float hv = sigf(g3) * tanhf(c);
                cx[ci] = c;
                float* hp = hxh + ((long)t * Bz + b) * Hz + hg;
                asm volatile("global_store_dword %0, %1, off sc0 sc1" :: "v"(hp), "v"(hv));
                ushort hi, lo;
                splitf(hv, hi, lo);
                ushort* hip = hxA_hi + wroff + ci;
                ushort* lop = hxA_lo + wroff + ci;
                asm volatile("global_store_short %0, %1, off sc0 sc1" :: "v"(hip), "v"((uint)hi));
                asm volatile("global_store_short %0, %1, off sc0 sc1" :: "v"(lop), "v"((uint)lo));
                // ---- publish: drain sc1 stores, then flag = t+1 ----
                asm volatile("s_waitcnt vmcnt(0)" ::: "memory");
                __syncthreads();
                if (tid == 0) st_sc1(&flags[wid * 16], (uint)(t + 1));
            }
        } else {
            if (t > 0) {
                int b = wid - 64, tt = t - 1;
                if (tid < 64) {
                    bool done = false;
                    while (!done) {
                        uint f = ld_sc1(&flags[tid * 16]);
                        done = (bool)__all(f >= (uint)t);
                        if (!done) __builtin_amdgcn_s_sleep(2);
                    }
                }
                __syncthreads();
                const float* hsrc = hxh + ((long)tt * Bz + b) * Hz + tid * 2;
                f32x2 h2;
                asm volatile("global_load_dwordx2 %0, %1, off sc0\n\ts_waitcnt vmcnt(0)"
                             : "=&v"(h2) : "v"(hsrc) : "memory");
                hxs[tid * 2] = h2[0];
                hxs[tid * 2 + 1] = h2[1];
                __syncthreads();
                int wv = tid >> 6;
                float hreg[16];
#pragma unroll
                for (int u = 0; u < 16; ++u) hreg[u] = hxs[lane * 16 + u];
                const float* eb = enc + (long)b * Sz * Hz;
                for (int s = wv; s < Sz; s += 8) {
                    const float* er = eb + (long)s * Hz + lane * 16;
                    float sum = 0.f;
#pragma unroll
                    for (int qq = 0; qq < 4; ++qq) {
                        float4 e4 = *(const float4*)(er + qq * 4);
                        sum += e4.x * hreg[qq*4] + e4.y * hreg[qq*4+1] + e4.z * hreg[qq*4+2] + e4.w * hreg[qq*4+3];
                    }
#pragma unroll
                    for (int off = 32; off >= 1; off >>= 1) sum += __shfl_xor(sum, off);
                    if (lane == 0) sc[s] = sum;
                }
                __syncthreads();
                if (tid < 64) {
                    float vv = (tid < Sz) ? sc[tid] : -3.402823e38f;
                    float mx = vv;
#pragma unroll
                    for (int off = 32; off >= 1; off >>= 1) mx = fmaxf(mx, __shfl_xor(mx, off));
                    float e = (tid < Sz) ? expf(vv - mx) : 0.f;
                    float ssum = e;
#pragma unroll
                    for (int off = 32; off >= 1; off >>= 1) ssum += __shfl_xor(ssum, off);
                    if (tid < Sz) aw[tid] = e / ssum;
                }
                __syncthreads();
                float c0 = 0.f, c1 = 0.f;
#pragma unroll 4
                for (int s = 0; s < Sz; ++s) {
                    float2 e2 = *(const float2*)(eb + (long)s * Hz + tid * 2);
                    float a = aw[s];
                    c0 += a * e2.x; c1 += a * e2.y;
                }
                long rr = (long)b * Tz + tt;
                ushort* dh = AH_hi + rr * 2048;
                ushort* dl = AH_lo + rr * 2048;
                ushort hi, lo;
                splitf(c0, hi, lo); dh[tid * 2]     = hi; dl[tid * 2]     = lo;
                splitf(c1, hi, lo); dh[tid * 2 + 1] = hi; dl[tid * 2 + 1] = lo;
                splitf(hxs[tid * 2],     hi, lo); dh[1024 + tid * 2]     = hi; dl[1024 + tid * 2]     = lo;
                splitf(hxs[tid * 2 + 1], hi, lo); dh[1024 + tid * 2 + 1] = hi; dl[1024 + tid * 2 + 1] = lo;
            }
        }
    }
}

// ---------- k_ht: HXA = tanh(AH @ Wht^T + bht) -> RN hi + residual lo ----------
__global__ __launch_bounds__(256, 1) void k_ht(const ushort* __restrict__ Ah,
                                               const ushort* __restrict__ Al,
                                               const ushort* __restrict__ Bh,
                                               const ushort* __restrict__ Bl,
                                               const float* __restrict__ bht,
                                               ushort* __restrict__ Hh, ushort* __restrict__ Hl) {
    __shared__ ushort sAh[128][40];
    __shared__ ushort sAl[128][40];
    __shared__ ushort sBh[128][40];
    __shared__ ushort sBl[128][40];
    int bid = blockIdx.x;
    int mt = bid >> 3, nt = bid & 7;
    int tid = threadIdx.x;
    int row = tid >> 1, half = tid & 1;
    int wv = tid >> 6, lane = tid & 63;
    int wr = wv >> 1, wc = wv & 1;
    int m0 = wr * 64, n0 = wc * 64;
    int r16 = lane & 15, kg = lane >> 4, k0 = kg * 8;

    f32x4 acc[4][4];
#pragma unroll
    for (int i = 0; i < 4; i++)
#pragma unroll
        for (int j = 0; j < 4; j++) acc[i][j] = (f32x4){0.f, 0.f, 0.f, 0.f};

    long arow = (long)(mt * 128 + row) * 2048;
    long brow = (long)(nt * 128 + row) * 2048;

    for (int kb = 0; kb < 2048; kb += 32) {
        const ushort* pa = Ah + arow + kb + half * 16;
        *(uint4*)&sAh[row][half * 16]     = *(const uint4*)pa;
        *(uint4*)&sAh[row][half * 16 + 8] = *(const uint4*)(pa + 8);
        const ushort* pl = Al + arow + kb + half * 16;
        *(uint4*)&sAl[row][half * 16]     = *(const uint4*)pl;
        *(uint4*)&sAl[row][half * 16 + 8] = *(const uint4*)(pl + 8);
        const ushort* pb = Bh + brow + kb + half * 16;
        *(uint4*)&sBh[row][half * 16]     = *(const uint4*)pb;
        *(uint4*)&sBh[row][half * 16 + 8] = *(const uint4*)(pb + 8);
        const ushort* pc = Bl + brow + kb + half * 16;
        *(uint4*)&sBl[row][half * 16]     = *(const uint4*)pc;
        *(uint4*)&sBl[row][half * 16 + 8] = *(const uint4*)(pc + 8);
        __syncthreads();
        bf16x8 af[4], alf[4], bhf[4], blf[4];
#pragma unroll
        for (int i = 0; i < 4; ++i) {
            af[i]  = *(const bf16x8*)&sAh[m0 + i * 16 + r16][k0];
            alf[i] = *(const bf16x8*)&sAl[m0 + i * 16 + r16][k0];
            bhf[i] = *(const bf16x8*)&sBh[n0 + i * 16 + r16][k0];
            blf[i] = *(const bf16x8*)&sBl[n0 + i * 16 + r16][k0];
        }
#pragma unroll
        for (int i = 0; i < 4; ++i)
#pragma unroll
            for (int jn = 0; jn < 4; ++jn) {
                acc[i][jn] = __builtin_amdgcn_mfma_f32_16x16x32_bf16(af[i],  bhf[jn], acc[i][jn], 0, 0, 0);
                acc[i][jn] = __builtin_amdgcn_mfma_f32_16x16x32_bf16(af[i],  blf[jn], acc[i][jn], 0, 0, 0);
                acc[i][jn] = __builtin_amdgcn_mfma_f32_16x16x32_bf16(alf[i], bhf[jn], acc[i][jn], 0, 0, 0);
            }
        __syncthreads();
    }
#pragma unroll
    for (int i = 0; i < 4; ++i) {
        int gr0 = mt * 128 + m0 + i * 16 + kg * 4;
#pragma unroll
        for (int reg = 0; reg < 4; ++reg) {
            int gr = gr0 + reg;
            bool valid = gr < Mz;
#pragma unroll
            for (int jn = 0; jn < 4; ++jn) {
                int gc = nt * 128 + n0 + jn * 16 + r16;
                float vv = tanhf(acc[i][jn][reg] + bht[gc]);
                ushort hi = 0, lo = 0;
                if (valid) splitrn(vv, hi, lo);
                Hh[(long)gr * Hz + gc] = hi;
                Hl[(long)gr * Hz + gc] = lo;
            }
        }
    }
}

// ---------- k_voc4: SINGLE-product bf16 logits GEMM + nt stores + per-tile max keys ----------
__global__ __launch_bounds__(256, 2) void k_voc4(
    const ushort* __restrict__ Ah, const ushort* __restrict__ Wh,
    const float* __restrict__ bvoc,
    float* __restrict__ out, ull* __restrict__ keys) {
    __shared__ ushort sAh[128][40];
    __shared__ ushort sBh[128][40];
    int bid = blockIdx.x;
    int nt = bid % 250, mg = bid / 250;       // mg in {0,1}
    int mt_beg = (mg == 0) ? 0 : 7;
    int mt_end = (mg == 0) ? 7 : 13;
    int tid = threadIdx.x;
    int row = tid >> 1, half = tid & 1;
    int wv = tid >> 6, lane = tid & 63;
    int wr = wv >> 1, wc = wv & 1;
    int m0 = wr * 64, n0 = wc * 64;
    int r16 = lane & 15, kg = lane >> 4, k0 = kg * 8;

    long wrow = (long)(nt * 128 + row) * Hz;
    int vcol_base = nt * 128 + n0;

    for (int mt = mt_beg; mt < mt_end; ++mt) {
        f32x4 acc[4][4];
#pragma unroll
        for (int i = 0; i < 4; i++)
#pragma unroll
            for (int j = 0; j < 4; j++) acc[i][j] = (f32x4){0.f, 0.f, 0.f, 0.f};

        long arow = (long)(mt * 128 + row) * Hz;

        for (int kb = 0; kb < Hz; kb += 32) {
            const ushort* pa = Ah + arow + kb + half * 16;
            *(uint4*)&sAh[row][half * 16]     = *(const uint4*)pa;
            *(uint4*)&sAh[row][half * 16 + 8] = *(const uint4*)(pa + 8);
            const ushort* pb = Wh + wrow + kb + half * 16;
            *(uint4*)&sBh[row][half * 16]     = *(const uint4*)pb;
            *(uint4*)&sBh[row][half * 16 + 8] = *(const uint4*)(pb + 8);
            __syncthreads();
            bf16x8 af[4], bhf[4];
#pragma unroll
            for (int i = 0; i < 4; ++i) {
                af[i]  = *(const bf16x8*)&sAh[m0 + i * 16 + r16][k0];
                bhf[i] = *(const bf16x8*)&sBh[n0 + i * 16 + r16][k0];
            }
#pragma unroll
            for (int i = 0; i < 4; ++i)
#pragma unroll
                for (int jn = 0; jn < 4; ++jn)
                    acc[i][jn] = __builtin_amdgcn_mfma_f32_16x16x32_bf16(af[i], bhf[jn], acc[i][jn], 0, 0, 0);
            __syncthreads();
        }
#pragma unroll
        for (int i = 0; i < 4; ++i) {
            int gr0 = mt * 128 + m0 + i * 16 + kg * 4;
#pragma unroll
            for (int reg = 0; reg < 4; ++reg) {
                int gr = gr0 + reg;
                bool valid = gr < Mz;
                float bestv = -3.402823e38f;
                int bestc = 0;
#pragma unroll
                for (int jn = 0; jn < 4; ++jn) {
                    int gc = vcol_base + jn * 16 + r16;
                    float v = acc[i][jn][reg] + bvoc[gc];
                    if (valid) __builtin_nontemporal_store(v, &out[(long)gr * Vz + gc]);
                    if (v > bestv) { bestv = v; bestc = gc; }
                }
#pragma unroll
                for (int off = 1; off < 16; off <<= 1) {
                    float ov = __shfl_xor(bestv, off);
                    int oc = __shfl_xor(bestc, off);
                    if (ov > bestv || (ov == bestv && oc < bestc)) { bestv = ov; bestc = oc; }
                }
                if (valid && r16 == 0) {
                    uint u = __builtin_bit_cast(uint, bestv);
                    u = (u & 0x80000000u) ? ~u : (u | 0x80000000u);
                    keys[(long)gr * 512 + nt * 2 + wc] = (((ull)u) << 32) | (ull)(65535 - bestc);
                }
            }
        }
    }
}

// ---------- k_argmax3: reduce per-tile keys -> per-row APPROX MAX VALUE ----------
__global__ __launch_bounds__(256) void k_argmax3(const ull* __restrict__ keys,
                                                 float* __restrict__ amax) {
    int r = blockIdx.x, tid = threadIdx.x;
    ull best = 0;
    for (int j = tid; j < 500; j += 256) {
        ull k = keys[(long)r * 512 + j];
        if (k > best) best = k;
    }
    __shared__ ull sk[256];
    sk[tid] = best;
    __syncthreads();
    for (int s = 128; s > 0; s >>= 1) {
        if (tid < s) { if (sk[tid + s] > sk[tid]) sk[tid] = sk[tid + s]; }
        __syncthreads();
    }
    if (tid == 0) {
        uint e = (uint)(sk[0] >> 32);
        uint orig = (e & 0x80000000u) ? (e & 0x7FFFFFFFu) : ~e;
        amax[r] = __builtin_bit_cast(float, orig);
    }
}

// ---------- k_rescan: exact fp32 re-evaluation of near-max candidates ----------
__global__ __launch_bounds__(256) void k_rescan(
    const float* __restrict__ out, const float* __restrict__ amax,
    const ushort* __restrict__ Ah, const ushort* __restrict__ Al,
    const float* __restrict__ Wvoc, const float* __restrict__ bvoc,
    float* __restrict__ pred) {
    int r = blockIdx.x, tid = threadIdx.x;
    __shared__ float arow[Hz];
    __shared__ int cand[CAP];
    __shared__ int ccnt;
    __shared__ float cval[4];
    __shared__ float sv[256];
    __shared__ int   si[256];
    if (tid == 0) ccnt = 0;
    float sq = 0.f;
#pragma unroll
    for (int u = 0; u < 4; ++u) {
        int j = tid + 256 * u;
        float a = bf2f(Ah[(long)r * Hz + j]) + bf2f(Al[(long)r * Hz + j]);
        arow[j] = a;
        sq += a * a;
    }
#pragma unroll
    for (int off = 32; off >= 1; off >>= 1) sq += __shfl_xor(sq, off);
    if ((tid & 63) == 0) cval[tid >> 6] = sq;
    __syncthreads();
    float nrm = sqrtf((cval[0] + cval[1]) + (cval[2] + cval[3]));
    float margin = 0.0094f * nrm + 0.01f;
    float thr = amax[r] - margin;
    __syncthreads();
    const float* rowp = out + (long)r * Vz;
    for (int c = tid; c < Vz; c += 256) {
        float v = rowp[c];
        if (v >= thr) {
            int slot = atomicAdd(&ccnt, 1);
            if (slot < CAP) cand[slot] = c;
        }
    }
    __syncthreads();
    int n = ccnt;
    int besti;
    if (n <= CAP) {
        float bestv = -3.402823e38f;
        besti = 0x7FFFFFFF;
        for (int k = 0; k < n; ++k) {
            int c = cand[k];
            const float* wr = Wvoc + (long)c * Hz;
            float s = 0.f;
#pragma unroll
            for (int u = 0; u < 4; ++u) {
                int j = tid + 256 * u;
                s += arow[j] * wr[j];
            }
#pragma unroll
            for (int off = 32; off >= 1; off >>= 1) s += __shfl_xor(s, off);
            if ((tid & 63) == 0) cval[tid >> 6] = s;
            __syncthreads();
            float tot = (cval[0] + cval[1]) + (cval[2] + cval[3]) + bvoc[c];
            if (tot > bestv || (tot == bestv && c < besti)) { bestv = tot; besti = c; }
            __syncthreads();
        }
    } else {
        float bv = -3.402823e38f;
        int bi = 0x7FFFFFFF;
        for (int c = tid; c < Vz; c += 256) {
            const float* wr = Wvoc + (long)c * Hz;
            float s = 0.f;
            for (int j = 0; j < Hz; j += 4) {
                float4 w4 = *(const float4*)(wr + j);
                s += arow[j] * w4.x + arow[j + 1] * w4.y + arow[j + 2] * w4.z + arow[j + 3] * w4.w;
            }
            s += bvoc[c];
            if (s > bv || (s == bv && c < bi)) { bv = s; bi = c; }
        }
        sv[tid] = bv; si[tid] = bi;
        __syncthreads();
        for (int s2 = 128; s2 > 0; s2 >>= 1) {
            if (tid < s2) {
                if (sv[tid + s2] > sv[tid] ||
                    (sv[tid + s2] == sv[tid] && si[tid + s2] < si[tid])) {
                    sv[tid] = sv[tid + s2]; si[tid] = si[tid + s2];
                }
            }
            __syncthreads();
        }
        besti = si[0];
    }
    if (tid == 0) pred[r] = (float)besti;
}

// ---------------- host ----------------
extern "C" void kernel_launch(void* const* d_in, const int* in_sizes, int n_in,
                              void* d_out, int out_size, void* d_ws, size_t ws_size,
                              hipStream_t stream) {
    const int*   tok  = (const int*)d_in[0];
    const float* enc  = (const float*)d_in[1];
    const float* h0   = (const float*)d_in[2];
    const float* c0   = (const float*)d_in[3];
    const float* emb  = (const float*)d_in[6];
    const float* Wih  = (const float*)d_in[7];
    const float* Whh  = (const float*)d_in[8];
    const float* bih  = (const float*)d_in[9];
    const float* bhh  = (const float*)d_in[10];
    const float* Wht  = (const float*)d_in[11];
    const float* bht  = (const float*)d_in[12];
    const float* Wvoc = (const float*)d_in[13];
    const float* bvoc = (const float*)d_in[14];
    float* out = (float*)d_out;

    char* base = (char*)d_ws;
    size_t off = 0;
    float*  gx      = (float*)(base + off);  off += (size_t)Mz * 4096 * 4;
    ushort* hxA_hi  = (ushort*)(base + off); off += (size_t)NSLOT * 32768 * 2;   // rotating slots
    ushort* hxA_lo  = (ushort*)(base + off); off += (size_t)NSLOT * 32768 * 2;
    float*  cx      = (float*)(base + off);  off += 32768 * 4;
    float*  hxh     = (float*)(base + off);  off += (size_t)Tz * Bz * Hz * 4;
    ushort* AH_hi   = (ushort*)(base + off); off += (size_t)Mp * 2048 * 2;
    ushort* AH_lo   = (ushort*)(base + off); off += (size_t)Mp * 2048 * 2;
    ushort* Whh_hi  = (ushort*)(base + off); off += (size_t)4096 * 1024 * 2;
    ushort* Whh_lo  = (ushort*)(base + off); off += (size_t)4096 * 1024 * 2;
    ushort* Wht_hi  = (ushort*)(base + off); off += (size_t)1024 * 2048 * 2;
    ushort* Wht_lo  = (ushort*)(base + off); off += (size_t)1024 * 2048 * 2;

    const size_t wvh_bytes  = (size_t)Vz * Hz * 2;
    const size_t surv_bytes = (size_t)Mp * 1024 * 2 * 2 + (size_t)Mz * 512 * 8 + 8192 + 8192;
    bool fused = ws_size >= off + wvh_bytes + surv_bytes;                        // ~158 MB

    ushort* Wvh; size_t off2;
    if (fused) {
        Wvh = (ushort*)(base + off);
        off2 = off + wvh_bytes;
    } else {
        Wvh = (ushort*)base;                    // aliased over then-dead recurrence region
        off2 = wvh_bytes;
    }
    ushort* HXA_hi  = (ushort*)(base + off2); off2 += (size_t)Mp * 1024 * 2;
    ushort* HXA_lo  = (ushort*)(base + off2); off2 += (size_t)Mp * 1024 * 2;
    ull*    keys    = (ull*)(base + off2);    off2 += (size_t)Mz * 512 * 8;
    float*  amax    = (float*)(base + off2);  off2 += 8192;
    uint*   flags   = (uint*)(base + off2);   off2 += 8192;

    k_pre<<<776, 256, 0, stream>>>(hxA_hi, hxA_lo, cx, AH_hi, AH_lo, flags, h0, c0);
    k_wsplit<<<1024, 256, 0, stream>>>(Whh, Whh_hi, Whh_lo, 4096 * 1024 / 4);
    k_wsplit<<<512, 256, 0, stream>>>(Wht, Wht_hi, Wht_lo, 1024 * 2048 / 4);
    k_xgemm<<<13 * 32, 256, 0, stream>>>(emb, tok, Wih, bih, bhh, gx);

    k_recfused8<<<fused ? 256 : 96, 512, 0, stream>>>(
        gx, Whh_hi, Whh_lo, hxA_hi, hxA_lo, hxh, cx, enc, AH_hi, AH_lo, flags,
        Wvoc, Wvh, fused ? 1 : 0);

    k_ht<<<13 * 8, 256, 0, stream>>>(AH_hi, AH_lo, Wht_hi, Wht_lo, bht, HXA_hi, HXA_lo);
    if (!fused) {
        k_wbf16<<<2048, 256, 0, stream>>>(Wvoc, Wvh, Vz * Hz / 4);
    }
    k_voc4<<<500, 256, 0, stream>>>(HXA_hi, Wvh, bvoc, out, keys);
    k_argmax3<<<Mz, 256, 0, stream>>>(keys, amax);
    k_rescan<<<Mz, 256, 0, stream>>>(out, amax, HXA_hi, HXA_lo, Wvoc, bvoc,
                                     out + (long)Mz * Vz);
}

// Round 15
// 982.787 us; speedup vs baseline: 1.1021x; 1.1021x over previous
//
#include <hip/hip_runtime.h>
#include <math.h>

typedef short bf16x8 __attribute__((ext_vector_type(8)));
typedef float f32x4 __attribute__((ext_vector_type(4)));
typedef float f32x2 __attribute__((ext_vector_type(2)));
typedef unsigned int uint;
typedef uint u32x4 __attribute__((ext_vector_type(4)));
typedef unsigned long long ull;
typedef unsigned short ushort;

#define Bz 32
#define Tz 50
#define Sz 40
#define Vz 32000
#define Dz 512
#define Hz 1024
#define Mz 1600
#define Mp 1664
#define CAP 1024
#define NSLOT 51
#define SENT 0xFFFFFFFFu

__device__ __forceinline__ ushort f2bf(float f) {           // round-to-nearest-even
    uint u = __builtin_bit_cast(uint, f);
    return (ushort)((u + 0x7FFFu + ((u >> 16) & 1u)) >> 16);
}
__device__ __forceinline__ float bf2f(ushort h) {
    uint u = ((uint)h) << 16;
    return __builtin_bit_cast(float, u);
}
// truncation split: f = hi + rem
__device__ __forceinline__ void splitf(float f, ushort& hi, ushort& lo) {
    uint u = __builtin_bit_cast(uint, f);
    hi = (ushort)(u >> 16);
    float rem = f - __builtin_bit_cast(float, u & 0xFFFF0000u);
    lo = (ushort)(__builtin_bit_cast(uint, rem) >> 16);
}
// RN split: hi = RN(f), lo = RN(f - hi)
__device__ __forceinline__ void splitrn(float f, ushort& hi, ushort& lo) {
    hi = f2bf(f);
    lo = f2bf(f - bf2f(hi));
}
__device__ __forceinline__ float sigf(float x) { return 1.f / (1.f + expf(-x)); }

__device__ __forceinline__ uint packHi(uint a, uint b) { return (a >> 16) | (b & 0xFFFF0000u); }
__device__ __forceinline__ uint packLo(uint a, uint b) { return (a & 0xFFFFu) | (b << 16); }
__device__ __forceinline__ uint chk4(u32x4 d) {
    return (uint)((d[0] == SENT) | (d[1] == SENT) | (d[2] == SENT) | (d[3] == SENT));
}

// ---------- k_pre: pack h0 -> hxP slot0; cx; AH pad; sentinel-fill hxP slots 1..50 + hxh ----------
__global__ __launch_bounds__(256) void k_pre(uint* hxP, float* cx,
                                             ushort* AH_hi, ushort* AH_lo, float* hxh,
                                             const float* h0, const float* c0) {
    const int S0 = 32768, S1 = 65536, S2 = 196608;
    const int S3 = S2 + 50 * 32768, S4 = S3 + 50 * 32768;
    int stride = gridDim.x * 256;
    for (int gid = blockIdx.x * 256 + threadIdx.x; gid < S4; gid += stride) {
        if (gid < S0) {
            float v = h0[gid];
            ushort hi, lo;
            splitf(v, hi, lo);
            hxP[gid] = ((uint)hi << 16) | lo;
        } else if (gid < S1) {
            cx[gid - S0] = c0[gid - S0];
        } else if (gid < S2) {
            int g = gid - S1;               // AH pad rows 1600..1663 (both planes)
            AH_hi[(long)Mz * 2048 + g] = 0;
            AH_lo[(long)Mz * 2048 + g] = 0;
        } else if (gid < S3) {
            hxP[32768 + (gid - S2)] = SENT;           // slots 1..50
        } else {
            ((uint*)hxh)[gid - S3] = SENT;            // hxh sentinel (NaN pattern)
        }
    }
}

// ---------- k_wsplit: fp32 -> bf16 hi/lo planes (truncation; recurrence weights) ----------
__global__ __launch_bounds__(256) void k_wsplit(const float* __restrict__ src,
                                                ushort* __restrict__ hi, ushort* __restrict__ lo,
                                                int n4) {
    int stride = gridDim.x * 256;
    for (int i = blockIdx.x * 256 + threadIdx.x; i < n4; i += stride) {
        float4 f = *(const float4*)(src + (long)i * 4);
        float vv[4] = {f.x, f.y, f.z, f.w};
        ushort h[4], l[4];
#pragma unroll
        for (int e = 0; e < 4; ++e) splitf(vv[e], h[e], l[e]);
        uint2 hp, lp;
        hp.x = (uint)h[0] | ((uint)h[1] << 16);
        hp.y = (uint)h[2] | ((uint)h[3] << 16);
        lp.x = (uint)l[0] | ((uint)l[1] << 16);
        lp.y = (uint)l[2] | ((uint)l[3] << 16);
        *(uint2*)(hi + (long)i * 4) = hp;
        *(uint2*)(lo + (long)i * 4) = lp;
    }
}

// ---------- k_wbf16: fp32 -> single bf16 RN plane (fallback for Wvoc) ----------
__global__ __launch_bounds__(256) void k_wbf16(const float* __restrict__ src,
                                               ushort* __restrict__ dst, int n4) {
    int stride = gridDim.x * 256;
    for (int i = blockIdx.x * 256 + threadIdx.x; i < n4; i += stride) {
        float4 f = *(const float4*)(src + (long)i * 4);
        uint2 hp;
        hp.x = (uint)f2bf(f.x) | ((uint)f2bf(f.y) << 16);
        hp.y = (uint)f2bf(f.z) | ((uint)f2bf(f.w) << 16);
        *(uint2*)(dst + (long)i * 4) = hp;
    }
}

// ---------- k_xgemm: gates_x = emb[tok] @ Wih^T + bih + bhh (split-bf16 MFMA) ----------
__global__ __launch_bounds__(256, 1) void k_xgemm(const float* __restrict__ emb,
                                                  const int* __restrict__ tok,
                                                  const float* __restrict__ Wih,
                                                  const float* __restrict__ bih,
                                                  const float* __restrict__ bhh,
                                                  float* __restrict__ gx) {
    __shared__ ushort sAh[128][40];
    __shared__ ushort sAl[128][40];
    __shared__ ushort sBh[128][40];
    __shared__ ushort sBl[128][40];
    int bid = blockIdx.x;
    int mt = bid >> 5, nt = bid & 31;
    int tid = threadIdx.x;
    int row = tid >> 1, half = tid & 1;
    int wv = tid >> 6, lane = tid & 63;
    int wr = wv >> 1, wc = wv & 1;
    int m0 = wr * 64, n0 = wc * 64;
    int r16 = lane & 15, kg = lane >> 4, k0 = kg * 8;

    f32x4 acc[4][4];
#pragma unroll
    for (int i = 0; i < 4; i++)
#pragma unroll
        for (int j = 0; j < 4; j++) acc[i][j] = (f32x4){0.f, 0.f, 0.f, 0.f};

    int r = mt * 128 + row;
    int tk = (r < Mz) ? tok[r] : 0;
    const float* arow = emb + (long)tk * Dz;
    const float* brow = Wih + (long)(nt * 128 + row) * Dz;

    for (int kb = 0; kb < Dz; kb += 32) {
        {
            ushort hh[16], ll[16];
#pragma unroll
            for (int q = 0; q < 16; q += 4) {
                float4 w4 = (r < Mz) ? *(const float4*)(arow + kb + half * 16 + q)
                                     : (float4){0.f, 0.f, 0.f, 0.f};
                float vv[4] = {w4.x, w4.y, w4.z, w4.w};
#pragma unroll
                for (int e = 0; e < 4; ++e) splitf(vv[e], hh[q + e], ll[q + e]);
            }
            *(uint4*)&sAh[row][half * 16]     = *(uint4*)&hh[0];
            *(uint4*)&sAh[row][half * 16 + 8] = *(uint4*)&hh[8];
            *(uint4*)&sAl[row][half * 16]     = *(uint4*)&ll[0];
            *(uint4*)&sAl[row][half * 16 + 8] = *(uint4*)&ll[8];
        }
        {
            ushort hh[16], ll[16];
#pragma unroll
            for (int q = 0; q < 16; q += 4) {
                float4 w4 = *(const float4*)(brow + kb + half * 16 + q);
                float vv[4] = {w4.x, w4.y, w4.z, w4.w};
#pragma unroll
                for (int e = 0; e < 4; ++e) splitf(vv[e], hh[q + e], ll[q + e]);
            }
            *(uint4*)&sBh[row][half * 16]     = *(uint4*)&hh[0];
            *(uint4*)&sBh[row][half * 16 + 8] = *(uint4*)&hh[8];
            *(uint4*)&sBl[row][half * 16]     = *(uint4*)&ll[0];
            *(uint4*)&sBl[row][half * 16 + 8] = *(uint4*)&ll[8];
        }
        __syncthreads();
        bf16x8 af[4], alf[4], bhf[4], blf[4];
#pragma unroll
        for (int i = 0; i < 4; ++i) {
            af[i]  = *(const bf16x8*)&sAh[m0 + i * 16 + r16][k0];
            alf[i] = *(const bf16x8*)&sAl[m0 + i * 16 + r16][k0];
            bhf[i] = *(const bf16x8*)&sBh[n0 + i * 16 + r16][k0];
            blf[i] = *(const bf16x8*)&sBl[n0 + i * 16 + r16][k0];
        }
#pragma unroll
        for (int i = 0; i < 4; ++i)
#pragma unroll
            for (int jn = 0; jn < 4; ++jn) {
                acc[i][jn] = __builtin_amdgcn_mfma_f32_16x16x32_bf16(af[i],  bhf[jn], acc[i][jn], 0, 0, 0);
                acc[i][jn] = __builtin_amdgcn_mfma_f32_16x16x32_bf16(af[i],  blf[jn], acc[i][jn], 0, 0, 0);
                acc[i][jn] = __builtin_amdgcn_mfma_f32_16x16x32_bf16(alf[i], bhf[jn], acc[i][jn], 0, 0, 0);
            }
        __syncthreads();
    }
#pragma unroll
    for (int i = 0; i < 4; ++i) {
        int gr0 = mt * 128 + m0 + i * 16 + kg * 4;
#pragma unroll
        for (int reg = 0; reg < 4; ++reg) {
            int gr = gr0 + reg;
            if (gr >= Mz) continue;
#pragma unroll
            for (int jn = 0; jn < 4; ++jn) {
                int gc = nt * 128 + n0 + jn * 16 + r16;
                gx[(long)gr * 4096 + gc] = acc[i][jn][reg] + bih[gc] + bhh[gc];
            }
        }
    }
}

// ---------- k_recfused9: SENTINEL data-polling (no flags, no drains); packed hx slots ----------
// hxP[t][row 32][col 1024] uint = (bf16hi<<16)|bf16lo. Slot t written once -> a word's value
// IS its ready-signal (SENT impossible for finite values). Consumers retry-load their slice.
__global__ __launch_bounds__(512, 1) void k_recfused9(
    const float* __restrict__ gx,
    const ushort* __restrict__ Whi, const ushort* __restrict__ Wlo,
    uint* __restrict__ hxP,
    float* __restrict__ hxh, float* __restrict__ cx,
    const float* __restrict__ enc,
    ushort* __restrict__ AH_hi, ushort* __restrict__ AH_lo,
    const float* __restrict__ Wvoc, ushort* __restrict__ Wvh,
    int do_wsplit) {
    __shared__ u32x4 stg4[8192];     // 128KB: hi[kslot128][row32 rot] + lo at +4096; sg aliased
    __shared__ float hxs[Hz];
    __shared__ float sc[64];
    __shared__ float aw[64];
    int wid = blockIdx.x, tid = threadIdx.x;

    if (wid >= 96) {
        if (do_wsplit) {
            int n4 = Vz * Hz / 4;
            int stride = 160 * 512;
            for (int i = (wid - 96) * 512 + tid; i < n4; i += stride) {
                float4 f = *(const float4*)(Wvoc + (long)i * 4);
                uint2 hp;
                hp.x = (uint)f2bf(f.x) | ((uint)f2bf(f.y) << 16);
                hp.y = (uint)f2bf(f.z) | ((uint)f2bf(f.w) << 16);
                *(uint2*)(Wvh + (long)i * 4) = hp;
            }
        }
        return;
    }

    int lane = tid & 63, kh = tid >> 6;

    for (int t = 0; t <= Tz; ++t) {
        if (wid < 64) {
            if (t < Tz) {
                int w = wid;
                long rdoff = (long)t * 32768;
                long wroff = (long)(t + 1) * 32768;
                int kslot = kh * 16 + (lane & 15);
                int rowb = (lane >> 4) * 8;
                const uint* bp = hxP + rdoff + (long)rowb * 1024 + kslot * 8;
                // ---- stage own K-slice: retry-load until no sentinel, unpack hi/lo ----
#pragma unroll
                for (int grp = 0; grp < 2; ++grp) {
                    const uint* g0 = bp + (long)grp * 4096;
                    u32x4 a0, b0, a1, b1, a2, b2, a3, b3;
                    while (1) {
                        asm volatile(
                            "global_load_dwordx4 %0, %8, off sc0 sc1\n\t"
                            "global_load_dwordx4 %1, %9, off sc0 sc1\n\t"
                            "global_load_dwordx4 %2, %10, off sc0 sc1\n\t"
                            "global_load_dwordx4 %3, %11, off sc0 sc1\n\t"
                            "global_load_dwordx4 %4, %12, off sc0 sc1\n\t"
                            "global_load_dwordx4 %5, %13, off sc0 sc1\n\t"
                            "global_load_dwordx4 %6, %14, off sc0 sc1\n\t"
                            "global_load_dwordx4 %7, %15, off sc0 sc1\n\t"
                            "s_waitcnt vmcnt(0)"
                            : "=&v"(a0), "=&v"(b0), "=&v"(a1), "=&v"(b1),
                              "=&v"(a2), "=&v"(b2), "=&v"(a3), "=&v"(b3)
                            : "v"(g0), "v"(g0 + 4), "v"(g0 + 1024), "v"(g0 + 1028),
                              "v"(g0 + 2048), "v"(g0 + 2052), "v"(g0 + 3072), "v"(g0 + 3076)
                            : "memory");
                        uint bad = chk4(a0) | chk4(b0) | chk4(a1) | chk4(b1)
                                 | chk4(a2) | chk4(b2) | chk4(a3) | chk4(b3);
                        if (__all(bad == 0)) break;
                        __builtin_amdgcn_s_sleep(1);
                    }
                    int li = kslot * 32;
#define STROW(rl, dA, dB)                                                            \
                    {                                                                \
                        int rr = rowb + grp * 4 + (rl);                              \
                        int idx = li + ((rr + kslot) & 31);                          \
                        u32x4 h4, l4;                                                \
                        h4[0] = packHi(dA[0], dA[1]); h4[1] = packHi(dA[2], dA[3]);  \
                        h4[2] = packHi(dB[0], dB[1]); h4[3] = packHi(dB[2], dB[3]);  \
                        l4[0] = packLo(dA[0], dA[1]); l4[1] = packLo(dA[2], dA[3]);  \
                        l4[2] = packLo(dB[0], dB[1]); l4[3] = packLo(dB[2], dB[3]);  \
                        stg4[idx] = h4; stg4[4096 + idx] = l4;                       \
                    }
                    STROW(0, a0, b0) STROW(1, a1, b1) STROW(2, a2, b2) STROW(3, a3, b3)
#undef STROW
                }
                // ---- MFMA: wave kh, its K-slice, all 4 gates ----
                int r16 = lane & 15, kg = lane >> 4;
                int jbase = w * 16 + r16;
                const ushort* whbase = Whi + (long)jbase * 1024;
                const ushort* wlbase = Wlo + (long)jbase * 1024;
                f32x4 acc[2][4];
#pragma unroll
                for (int i = 0; i < 2; ++i)
#pragma unroll
                    for (int v = 0; v < 4; ++v) acc[i][v] = (f32x4){0.f, 0.f, 0.f, 0.f};
#pragma unroll
                for (int it = 0; it < 4; ++it) {
                    int ksl = kh * 16 + it * 4 + kg;
                    int k0 = ksl * 8;
                    bf16x8 a_h0 = *(const bf16x8*)&stg4[       ksl * 32 + ((r16 + ksl) & 31)];
                    bf16x8 a_l0 = *(const bf16x8*)&stg4[4096 + ksl * 32 + ((r16 + ksl) & 31)];
                    bf16x8 a_h1 = *(const bf16x8*)&stg4[       ksl * 32 + ((16 + r16 + ksl) & 31)];
                    bf16x8 a_l1 = *(const bf16x8*)&stg4[4096 + ksl * 32 + ((16 + r16 + ksl) & 31)];
                    bf16x8 bh[4], bl[4];
#pragma unroll
                    for (int v = 0; v < 4; ++v) {
                        bh[v] = *(const bf16x8*)(whbase + ((long)v << 20) + k0);
                        bl[v] = *(const bf16x8*)(wlbase + ((long)v << 20) + k0);
                    }
#pragma unroll
                    for (int v = 0; v < 4; ++v) {
                        acc[0][v] = __builtin_amdgcn_mfma_f32_16x16x32_bf16(a_h0, bh[v], acc[0][v], 0, 0, 0);
                        acc[0][v] = __builtin_amdgcn_mfma_f32_16x16x32_bf16(a_l0, bh[v], acc[0][v], 0, 0, 0);
                        acc[0][v] = __builtin_amdgcn_mfma_f32_16x16x32_bf16(a_h0, bl[v], acc[0][v], 0, 0, 0);
                        acc[1][v] = __builtin_amdgcn_mfma_f32_16x16x32_bf16(a_h1, bh[v], acc[1][v], 0, 0, 0);
                        acc[1][v] = __builtin_amdgcn_mfma_f32_16x16x32_bf16(a_l1, bh[v], acc[1][v], 0, 0, 0);
                        acc[1][v] = __builtin_amdgcn_mfma_f32_16x16x32_bf16(a_h1, bl[v], acc[1][v], 0, 0, 0);
                    }
                }
                __syncthreads();                 // staged A dead; alias sg onto stg4
                float* sgp = (float*)stg4;       // sg[kh 8][v 4][b 32][h16 16] = 64KB
#pragma unroll
                for (int i = 0; i < 2; ++i)
#pragma unroll
                    for (int v = 0; v < 4; ++v)
#pragma unroll
                        for (int reg = 0; reg < 4; ++reg)
                            sgp[(((kh * 4 + v) * 32) + i * 16 + kg * 4 + reg) * 16 + r16] = acc[i][v][reg];
                __syncthreads();
                // ---- cell: thread = (b, h16) ----
                int b = tid >> 4, h16 = tid & 15;
                int hg = w * 16 + h16;
                const float* gxr = gx + ((long)b * Tz + t) * 4096 + hg;
                float g0s = 0.f, g1s = 0.f, g2s = 0.f, g3s = 0.f;
#pragma unroll
                for (int khh = 0; khh < 8; ++khh) {
                    g0s += sgp[((khh * 4 + 0) * 32 + b) * 16 + h16];
                    g1s += sgp[((khh * 4 + 1) * 32 + b) * 16 + h16];
                    g2s += sgp[((khh * 4 + 2) * 32 + b) * 16 + h16];
                    g3s += sgp[((khh * 4 + 3) * 32 + b) * 16 + h16];
                }
                g0s += gxr[0]; g1s += gxr[1024]; g2s += gxr[2048]; g3s += gxr[3072];
                long ci = (long)b * Hz + hg;
                float c = sigf(g1s) * cx[ci] + sigf(g0s) * tanhf(g2s);
                float hv = sigf(g3s) * tanhf(c);
                cx[ci] = c;
                float* hp = hxh + ((long)t * Bz + b) * Hz + hg;
                asm volatile("global_store_dword %0, %1, off sc0 sc1" :: "v"(hp), "v"(hv));
                ushort hi, lo;
                splitf(hv, hi, lo);
                uint pk = ((uint)hi << 16) | lo;        // never SENT (finite value)
                uint* pp = hxP + wroff + ci;
                asm volatile("global_store_dword %0, %1, off sc0 sc1" :: "v"(pp), "v"(pk));
                __syncthreads();                 // protect sgp reads from next step's staging
            }
        } else {
            if (t > 0) {
                int b = wid - 64, tt = t - 1;
                const float* hsrc = hxh + ((long)tt * Bz + b) * Hz + tid * 2;
                f32x2 h2;
                while (1) {                      // per-thread sentinel poll on own 2 words
                    asm volatile("global_load_dwordx2 %0, %1, off sc0 sc1\n\ts_waitcnt vmcnt(0)"
                                 : "=&v"(h2) : "v"(hsrc) : "memory");
                    uint u0 = __builtin_bit_cast(uint, h2[0]);
                    uint u1 = __builtin_bit_cast(uint, h2[1]);
                    if (u0 != SENT && u1 != SENT) break;
                    __builtin_amdgcn_s_sleep(2);
                }
                hxs[tid * 2] = h2[0];
                hxs[tid * 2 + 1] = h2[1];
                __syncthreads();
                int wv = tid >> 6;
                float hreg[16];
#pragma unroll
                for (int u = 0; u < 16; ++u) hreg[u] = hxs[lane * 16 + u];
                const float* eb = enc + (long)b * Sz * Hz;
                for (int s = wv; s < Sz; s += 8) {
                    const float* er = eb + (long)s * Hz + lane * 16;
                    float sum = 0.f;
#pragma unroll
                    for (int qq = 0; qq < 4; ++qq) {
                        float4 e4 = *(const float4*)(er + qq * 4);
                        sum += e4.x * hreg[qq*4] + e4.y * hreg[qq*4+1] + e4.z * hreg[qq*4+2] + e4.w * hreg[qq*4+3];
                    }
#pragma unroll
                    for (int off = 32; off >= 1; off >>= 1) sum += __shfl_xor(sum, off);
                    if (lane == 0) sc[s] = sum;
                }
                __syncthreads();
                if (tid < 64) {
                    float vv = (tid < Sz) ? sc[tid] : -3.402823e38f;
                    float mx = vv;
#pragma unroll
                    for (int off = 32; off >= 1; off >>= 1) mx = fmaxf(mx, __shfl_xor(mx, off));
                    float e = (tid < Sz) ? expf(vv - mx) : 0.f;
                    float ssum = e;
#pragma unroll
                    for (int off = 32; off >= 1; off >>= 1) ssum += __shfl_xor(ssum, off);
                    if (tid < Sz) aw[tid] = e / ssum;
                }
                __syncthreads();
                float c0 = 0.f, c1 = 0.f;
#pragma unroll 4
                for (int s = 0; s < Sz; ++s) {
                    float2 e2 = *(const float2*)(eb + (long)s * Hz + tid * 2);
                    float a = aw[s];
                    c0 += a * e2.x; c1 += a * e2.y;
                }
                long rr = (long)b * Tz + tt;
                ushort* dh = AH_hi + rr * 2048;
                ushort* dl = AH_lo + rr * 2048;
                ushort hi, lo;
                splitf(c0, hi, lo); dh[tid * 2]     = hi; dl[tid * 2]     = lo;
                splitf(c1, hi, lo); dh[tid * 2 + 1] = hi; dl[tid * 2 + 1] = lo;
                splitf(hxs[tid * 2],     hi, lo); dh[1024 + tid * 2]     = hi; dl[1024 + tid * 2]     = lo;
                splitf(hxs[tid * 2 + 1], hi, lo); dh[1024 + tid * 2 + 1] = hi; dl[1024 + tid * 2 + 1] = lo;
                __syncthreads();
            }
        }
    }
}

// ---------- k_ht: HXA = tanh(AH @ Wht^T + bht) -> RN hi + residual lo ----------
__global__ __launch_bounds__(256, 1) void k_ht(const ushort* __restrict__ Ah,
                                               const ushort* __restrict__ Al,
                                               const ushort* __restrict__ Bh,
                                               const ushort* __restrict__ Bl,
                                               const float* __restrict__ bht,
                                               ushort* __restrict__ Hh, ushort* __restrict__ Hl) {
    __shared__ ushort sAh[128][40];
    __shared__ ushort sAl[128][40];
    __shared__ ushort sBh[128][40];
    __shared__ ushort sBl[128][40];
    int bid = blockIdx.x;
    int mt = bid >> 3, nt = bid & 7;
    int tid = threadIdx.x;
    int row = tid >> 1, half = tid & 1;
    int wv = tid >> 6, lane = tid & 63;
    int wr = wv >> 1, wc = wv & 1;
    int m0 = wr * 64, n0 = wc * 64;
    int r16 = lane & 15, kg = lane >> 4, k0 = kg * 8;

    f32x4 acc[4][4];
#pragma unroll
    for (int i = 0; i < 4; i++)
#pragma unroll
        for (int j = 0; j < 4; j++) acc[i][j] = (f32x4){0.f, 0.f, 0.f, 0.f};

    long arow = (long)(mt * 128 + row) * 2048;
    long brow = (long)(nt * 128 + row) * 2048;

    for (int kb = 0; kb < 2048; kb += 32) {
        const ushort* pa = Ah + arow + kb + half * 16;
        *(uint4*)&sAh[row][half * 16]     = *(const uint4*)pa;
        *(uint4*)&sAh[row][half * 16 + 8] = *(const uint4*)(pa + 8);
        const ushort* pl = Al + arow + kb + half * 16;
        *(uint4*)&sAl[row][half * 16]     = *(const uint4*)pl;
        *(uint4*)&sAl[row][half * 16 + 8] = *(const uint4*)(pl + 8);
        const ushort* pb = Bh + brow + kb + half * 16;
        *(uint4*)&sBh[row][half * 16]     = *(const uint4*)pb;
        *(uint4*)&sBh[row][half * 16 + 8] = *(const uint4*)(pb + 8);
        const ushort* pc = Bl + brow + kb + half * 16;
        *(uint4*)&sBl[row][half * 16]     = *(const uint4*)pc;
        *(uint4*)&sBl[row][half * 16 + 8] = *(const uint4*)(pc + 8);
        __syncthreads();
        bf16x8 af[4], alf[4], bhf[4], blf[4];
#pragma unroll
        for (int i = 0; i < 4; ++i) {
            af[i]  = *(const bf16x8*)&sAh[m0 + i * 16 + r16][k0];
            alf[i] = *(const bf16x8*)&sAl[m0 + i * 16 + r16][k0];
            bhf[i] = *(const bf16x8*)&sBh[n0 + i * 16 + r16][k0];
            blf[i] = *(const bf16x8*)&sBl[n0 + i * 16 + r16][k0];
        }
#pragma unroll
        for (int i = 0; i < 4; ++i)
#pragma unroll
            for (int jn = 0; jn < 4; ++jn) {
                acc[i][jn] = __builtin_amdgcn_mfma_f32_16x16x32_bf16(af[i],  bhf[jn], acc[i][jn], 0, 0, 0);
                acc[i][jn] = __builtin_amdgcn_mfma_f32_16x16x32_bf16(af[i],  blf[jn], acc[i][jn], 0, 0, 0);
                acc[i][jn] = __builtin_amdgcn_mfma_f32_16x16x32_bf16(alf[i], bhf[jn], acc[i][jn], 0, 0, 0);
            }
        __syncthreads();
    }
#pragma unroll
    for (int i = 0; i < 4; ++i) {
        int gr0 = mt * 128 + m0 + i * 16 + kg * 4;
#pragma unroll
        for (int reg = 0; reg < 4; ++reg) {
            int gr = gr0 + reg;
            bool valid = gr < Mz;
#pragma unroll
            for (int jn = 0; jn < 4; ++jn) {
                int gc = nt * 128 + n0 + jn * 16 + r16;
                float vv = tanhf(acc[i][jn][reg] + bht[gc]);
                ushort hi = 0, lo = 0;
                if (valid) splitrn(vv, hi, lo);
                Hh[(long)gr * Hz + gc] = hi;
                Hl[(long)gr * Hz + gc] = lo;
            }
        }
    }
}

// ---------- k_voc4: SINGLE-product bf16 logits GEMM + nt stores + per-tile max keys ----------
__global__ __launch_bounds__(256, 2) void k_voc4(
    const ushort* __restrict__ Ah, const ushort* __restrict__ Wh,
    const float* __restrict__ bvoc,
    float* __restrict__ out, ull* __restrict__ keys) {
    __shared__ ushort sAh[128][40];
    __shared__ ushort sBh[128][40];
    int bid = blockIdx.x;
    int nt = bid % 250, mg = bid / 250;       // mg in {0,1}
    int mt_beg = (mg == 0) ? 0 : 7;
    int mt_end = (mg == 0) ? 7 : 13;
    int tid = threadIdx.x;
    int row = tid >> 1, half = tid & 1;
    int wv = tid >> 6, lane = tid & 63;
    int wr = wv >> 1, wc = wv & 1;
    int m0 = wr * 64, n0 = wc * 64;
    int r16 = lane & 15, kg = lane >> 4, k0 = kg * 8;

    long wrow = (long)(nt * 128 + row) * Hz;
    int vcol_base = nt * 128 + n0;

    for (int mt = mt_beg; mt < mt_end; ++mt) {
        f32x4 acc[4][4];
#pragma unroll
        for (int i = 0; i < 4; i++)
#pragma unroll
            for (int j = 0; j < 4; j++) acc[i][j] = (f32x4){0.f, 0.f, 0.f, 0.f};

        long arow = (long)(mt * 128 + row) * Hz;

        for (int kb = 0; kb < Hz; kb += 32) {
            const ushort* pa = Ah + arow + kb + half * 16;
            *(uint4*)&sAh[row][half * 16]     = *(const uint4*)pa;
            *(uint4*)&sAh[row][half * 16 + 8] = *(const uint4*)(pa + 8);
            const ushort* pb = Wh + wrow + kb + half * 16;
            *(uint4*)&sBh[row][half * 16]     = *(const uint4*)pb;
            *(uint4*)&sBh[row][half * 16 + 8] = *(const uint4*)(pb + 8);
            __syncthreads();
            bf16x8 af[4], bhf[4];
#pragma unroll
            for (int i = 0; i < 4; ++i) {
                af[i]  = *(const bf16x8*)&sAh[m0 + i * 16 + r16][k0];
                bhf[i] = *(const bf16x8*)&sBh[n0 + i * 16 + r16][k0];
            }
#pragma unroll
            for (int i = 0; i < 4; ++i)
#pragma unroll
                for (int jn = 0; jn < 4; ++jn)
                    acc[i][jn] = __builtin_amdgcn_mfma_f32_16x16x32_bf16(af[i], bhf[jn], acc[i][jn], 0, 0, 0);
            __syncthreads();
        }
#pragma unroll
        for (int i = 0; i < 4; ++i) {
            int gr0 = mt * 128 + m0 + i * 16 + kg * 4;
#pragma unroll
            for (int reg = 0; reg < 4; ++reg) {
                int gr = gr0 + reg;
                bool valid = gr < Mz;
                float bestv = -3.402823e38f;
                int bestc = 0;
#pragma unroll
                for (int jn = 0; jn < 4; ++jn) {
                    int gc = vcol_base + jn * 16 + r16;
                    float v = acc[i][jn][reg] + bvoc[gc];
                    if (valid) __builtin_nontemporal_store(v, &out[(long)gr * Vz + gc]);
                    if (v > bestv) { bestv = v; bestc = gc; }
                }
#pragma unroll
                for (int off = 1; off < 16; off <<= 1) {
                    float ov = __shfl_xor(bestv, off);
                    int oc = __shfl_xor(bestc, off);
                    if (ov > bestv || (ov == bestv && oc < bestc)) { bestv = ov; bestc = oc; }
                }
                if (valid && r16 == 0) {
                    uint u = __builtin_bit_cast(uint, bestv);
                    u = (u & 0x80000000u) ? ~u : (u | 0x80000000u);
                    keys[(long)gr * 512 + nt * 2 + wc] = (((ull)u) << 32) | (ull)(65535 - bestc);
                }
            }
        }
    }
}

// ---------- k_rescan2: amax from keys + TILE-PRUNED candidate scan + exact recompute ----------
__global__ __launch_bounds__(256) void k_rescan2(
    const float* __restrict__ out, const ull* __restrict__ keys,
    const ushort* __restrict__ Ah, const ushort* __restrict__ Al,
    const float* __restrict__ Wvoc, const float* __restrict__ bvoc,
    float* __restrict__ pred) {
    int r = blockIdx.x, tid = threadIdx.x;
    __shared__ float arow[Hz];
    __shared__ int cand[CAP];
    __shared__ int ccnt;
    __shared__ float cval[4];
    __shared__ ull sk[256];
    __shared__ float sv[256];
    __shared__ int   si[256];
    if (tid == 0) ccnt = 0;
    float sq = 0.f;
#pragma unroll
    for (int u = 0; u < 4; ++u) {
        int j = tid + 256 * u;
        float a = bf2f(Ah[(long)r * Hz + j]) + bf2f(Al[(long)r * Hz + j]);
        arow[j] = a;
        sq += a * a;
    }
#pragma unroll
    for (int off = 32; off >= 1; off >>= 1) sq += __shfl_xor(sq, off);
    if ((tid & 63) == 0) cval[tid >> 6] = sq;
    // amax from the 500 per-tile keys (monotonic encoding)
    ull best = 0;
    for (int j = tid; j < 500; j += 256) {
        ull k = keys[(long)r * 512 + j];
        if (k > best) best = k;
    }
    sk[tid] = best;
    __syncthreads();
    for (int s = 128; s > 0; s >>= 1) {
        if (tid < s) { if (sk[tid + s] > sk[tid]) sk[tid] = sk[tid + s]; }
        __syncthreads();
    }
    uint e0 = (uint)(sk[0] >> 32);
    uint ob0 = (e0 & 0x80000000u) ? (e0 & 0x7FFFFFFFu) : ~e0;
    float amaxv = __builtin_bit_cast(float, ob0);
    float nrm = sqrtf((cval[0] + cval[1]) + (cval[2] + cval[3]));
    float margin = 0.0094f * nrm + 0.01f;
    float thr = amaxv - margin;
    __syncthreads();
    // tile-pruned candidate collection (only tiles whose max >= thr)
    for (int j = tid; j < 500; j += 256) {
        ull k = keys[(long)r * 512 + j];
        uint e = (uint)(k >> 32);
        uint ob = (e & 0x80000000u) ? (e & 0x7FFFFFFFu) : ~e;
        float tv = __builtin_bit_cast(float, ob);
        if (tv >= thr) {
            int cb = (j >> 1) * 128 + (j & 1) * 64;
            for (int c2 = 0; c2 < 64; ++c2) {
                float v = out[(long)r * Vz + cb + c2];
                if (v >= thr) {
                    int slot = atomicAdd(&ccnt, 1);
                    if (slot < CAP) cand[slot] = cb + c2;
                }
            }
        }
    }
    __syncthreads();
    int n = ccnt;
    int besti;
    if (n <= CAP) {
        float bestv = -3.402823e38f;
        besti = 0x7FFFFFFF;
        for (int k = 0; k < n; ++k) {
            int c = cand[k];
            const float* wr = Wvoc + (long)c * Hz;
            float s = 0.f;
#pragma unroll
            for (int u = 0; u < 4; ++u) {
                int j = tid + 256 * u;
                s += arow[j] * wr[j];
            }
#pragma unroll
            for (int off = 32; off >= 1; off >>= 1) s += __shfl_xor(s, off);
            if ((tid & 63) == 0) cval[tid >> 6] = s;
            __syncthreads();
            float tot = (cval[0] + cval[1]) + (cval[2] + cval[3]) + bvoc[c];
            if (tot > bestv || (tot == bestv && c < besti)) { bestv = tot; besti = c; }
            __syncthreads();
        }
    } else {
        float bv = -3.402823e38f;
        int bi = 0x7FFFFFFF;
        for (int c = tid; c < Vz; c += 256) {
            const float* wr = Wvoc + (long)c * Hz;
            float s = 0.f;
            for (int j = 0; j < Hz; j += 4) {
                float4 w4 = *(const float4*)(wr + j);
                s += arow[j] * w4.x + arow[j + 1] * w4.y + arow[j + 2] * w4.z + arow[j + 3] * w4.w;
            }
            s += bvoc[c];
            if (s > bv || (s == bv && c < bi)) { bv = s; bi = c; }
        }
        sv[tid] = bv; si[tid] = bi;
        __syncthreads();
        for (int s2 = 128; s2 > 0; s2 >>= 1) {
            if (tid < s2) {
                if (sv[tid + s2] > sv[tid] ||
                    (sv[tid + s2] == sv[tid] && si[tid + s2] < si[tid])) {
                    sv[tid] = sv[tid + s2]; si[tid] = si[tid + s2];
                }
            }
            __syncthreads();
        }
        besti = si[0];
    }
    if (tid == 0) pred[r] = (float)besti;
}

// ---------------- host ----------------
extern "C" void kernel_launch(void* const* d_in, const int* in_sizes, int n_in,
                              void* d_out, int out_size, void* d_ws, size_t ws_size,
                              hipStream_t stream) {
    const int*   tok  = (const int*)d_in[0];
    const float* enc  = (const float*)d_in[1];
    const float* h0   = (const float*)d_in[2];
    const float* c0   = (const float*)d_in[3];
    const float* emb  = (const float*)d_in[6];
    const float* Wih  = (const float*)d_in[7];
    const float* Whh  = (const float*)d_in[8];
    const float* bih  = (const float*)d_in[9];
    const float* bhh  = (const float*)d_in[10];
    const float* Wht  = (const float*)d_in[11];
    const float* bht  = (const float*)d_in[12];
    const float* Wvoc = (const float*)d_in[13];
    const float* bvoc = (const float*)d_in[14];
    float* out = (float*)d_out;

    char* base = (char*)d_ws;
    size_t off = 0;
    float*  gx      = (float*)(base + off);  off += (size_t)Mz * 4096 * 4;
    uint*   hxP     = (uint*)(base + off);   off += (size_t)NSLOT * 32768 * 4;   // packed rotating slots
    float*  cx      = (float*)(base + off);  off += 32768 * 4;
    float*  hxh     = (float*)(base + off);  off += (size_t)Tz * Bz * Hz * 4;
    ushort* AH_hi   = (ushort*)(base + off); off += (size_t)Mp * 2048 * 2;
    ushort* AH_lo   = (ushort*)(base + off); off += (size_t)Mp * 2048 * 2;
    ushort* Whh_hi  = (ushort*)(base + off); off += (size_t)4096 * 1024 * 2;
    ushort* Whh_lo  = (ushort*)(base + off); off += (size_t)4096 * 1024 * 2;
    ushort* Wht_hi  = (ushort*)(base + off); off += (size_t)1024 * 2048 * 2;
    ushort* Wht_lo  = (ushort*)(base + off); off += (size_t)1024 * 2048 * 2;

    const size_t wvh_bytes  = (size_t)Vz * Hz * 2;
    const size_t surv_bytes = (size_t)Mp * 1024 * 2 * 2 + (size_t)Mz * 512 * 8 + 8192;
    bool fused = ws_size >= off + wvh_bytes + surv_bytes;

    ushort* Wvh; size_t off2;
    if (fused) {
        Wvh = (ushort*)(base + off);
        off2 = off + wvh_bytes;
    } else {
        Wvh = (ushort*)base;                    // aliased over then-dead recurrence region
        off2 = wvh_bytes;
    }
    ushort* HXA_hi  = (ushort*)(base + off2); off2 += (size_t)Mp * 1024 * 2;
    ushort* HXA_lo  = (ushort*)(base + off2); off2 += (size_t)Mp * 1024 * 2;
    ull*    keys    = (ull*)(base + off2);    off2 += (size_t)Mz * 512 * 8;

    k_pre<<<4096, 256, 0, stream>>>(hxP, cx, AH_hi, AH_lo, hxh, h0, c0);
    k_wsplit<<<1024, 256, 0, stream>>>(Whh, Whh_hi, Whh_lo, 4096 * 1024 / 4);
    k_wsplit<<<512, 256, 0, stream>>>(Wht, Wht_hi, Wht_lo, 1024 * 2048 / 4);
    k_xgemm<<<13 * 32, 256, 0, stream>>>(emb, tok, Wih, bih, bhh, gx);

    k_recfused9<<<fused ? 256 : 96, 512, 0, stream>>>(
        gx, Whh_hi, Whh_lo, hxP, hxh, cx, enc, AH_hi, AH_lo, Wvoc, Wvh, fused ? 1 : 0);

    k_ht<<<13 * 8, 256, 0, stream>>>(AH_hi, AH_lo, Wht_hi, Wht_lo, bht, HXA_hi, HXA_lo);
    if (!fused) {
        k_wbf16<<<2048, 256, 0, stream>>>(Wvoc, Wvh, Vz * Hz / 4);
    }
    k_voc4<<<500, 256, 0, stream>>>(HXA_hi, Wvh, bvoc, out, keys);
    k_rescan2<<<Mz, 256, 0, stream>>>(out, keys, HXA_hi, HXA_lo, Wvoc, bvoc,
                                      out + (long)Mz * Vz);
}